// Round 2
// baseline (339.588 us; speedup 1.0000x reference)
//
#include <hip/hip_runtime.h>
#include <math.h>

// Output row layout (70 floats): [coords(3) | enc(64) | colours(3)]
// enc[2j]   = sin(i / 10000^(j/32)), enc[2j+1] = cos(...)
// All indices fit in uint32 (total = 70e6), so division by 70 is a cheap
// magic-multiply; only ONE per thread, then incremental (row,col) update.

#define OUTC 70u

__global__ __launch_bounds__(256) void pe_kernel(const float* __restrict__ pc,
                                                 float* __restrict__ out,
                                                 unsigned total) {
    __shared__ double s_invfreq[32];
    const int tid = threadIdx.x;
    if (tid < 32) {
        // 1 / 10000^(j/32) in double (rel err ~1e-16)
        s_invfreq[tid] = exp(-(double)tid * (log(10000.0) / 32.0));
    }
    __syncthreads();

    const unsigned q = blockIdx.x * 256u + (unsigned)tid;  // float4 index
    const unsigned base = q * 4u;
    if (base >= total) return;

    unsigned row = base / OUTC;            // u32 magic-mul division (cheap)
    unsigned col = base - row * OUTC;

    const double two_pi     = 6.283185307179586476925286766559;
    const double inv_two_pi = 0.15915494309189533576888376337251;

    float4 v;
    float* ve = &v.x;

#pragma unroll
    for (int k = 0; k < 4; ++k) {
        float r;
        if (col < 3u) {
            r = pc[row * 6u + col];                    // coords
        } else if (col >= 67u) {
            r = pc[row * 6u + (col - 64u)];            // colours
        } else {
            const unsigned e = col - 3u;               // 0..63
            const unsigned j = e >> 1;                 // 0..31
            const double arg = (double)(int)row * s_invfreq[j];
            // range-reduce in double: |red| <= pi
            const double kk  = rint(arg * inv_two_pi);
            const double red = fma(-kk, two_pi, arg);
            float s, c;
            __sincosf((float)red, &s, &c);
            r = (e & 1u) ? c : s;
        }
        ve[k] = r;
        if (++col == OUTC) { col = 0u; ++row; }        // incremental, no div
    }

    if (base + 3u < total) {
        reinterpret_cast<float4*>(out)[q] = v;         // 16B coalesced store
    } else {
        for (unsigned k = 0; k < 4u; ++k)
            if (base + k < total) out[base + k] = ve[k];
    }
}

extern "C" void kernel_launch(void* const* d_in, const int* in_sizes, int n_in,
                              void* d_out, int out_size, void* d_ws, size_t ws_size,
                              hipStream_t stream) {
    const float* pc = (const float*)d_in[0];
    float* out = (float*)d_out;
    const unsigned n = (unsigned)(in_sizes[0] / 6);    // rows
    const unsigned total = n * OUTC;                   // output elements
    const unsigned n_threads = (total + 3u) / 4u;
    const int block = 256;
    const unsigned grid = (n_threads + block - 1u) / block;
    pe_kernel<<<dim3(grid), dim3(block), 0, stream>>>(pc, out, total);
}

// Round 3
// 292.736 us; speedup vs baseline: 1.1601x; 1.1601x over previous
//
#include <hip/hip_runtime.h>
#include <math.h>

// Output row (70 floats): [coords(3) | enc(64) | colours(3)]
// enc[2j] = sin(i * 10^(-j/8)), enc[2j+1] = cos(...), j = 0..31
//
// Design: 32 rows per block staged in LDS (2240 floats = 560 float4s exactly;
// block global base 2240*b is float4-aligned even though the 70-float row
// stride is not). Phase A computes enc pairs divergence-free (1 sincos per
// 2 outputs, native __sinf/__cosf) + scatters coords/colours from coalesced
// float4 input loads. Phase B streams LDS -> global as aligned float4s.

#define ROWS_PER_BLOCK 32
#define OUTC 70
#define FLOATS_PER_BLOCK (ROWS_PER_BLOCK * OUTC)     // 2240
#define VEC4_PER_BLOCK   (FLOATS_PER_BLOCK / 4)      // 560
#define IN_FLOATS_PER_BLOCK (ROWS_PER_BLOCK * 6)     // 192
#define IN_VEC4_PER_BLOCK   (IN_FLOATS_PER_BLOCK/4)  // 48

__global__ __launch_bounds__(256) void pe_kernel(const float* __restrict__ pc,
                                                 float* __restrict__ out,
                                                 int n_rows) {
    __shared__ float  s_tile[FLOATS_PER_BLOCK];
    __shared__ double s_w2[32];          // 10^(-j/8) / (2*pi)

    const int tid = threadIdx.x;
    const int b = blockIdx.x;
    const int rowBase = b * ROWS_PER_BLOCK;

    if (tid < 32) {
        // inv_two_pi * 10000^(-tid/32); log() folds at compile time
        s_w2[tid] = 0.15915494309189533577 * exp(-(double)tid * (log(10000.0) / 32.0));
    }
    __syncthreads();

    // ---- Phase A1: enc pairs into LDS (uniform, no divergence) ----
    const int j = tid & 31;              // same j for all 4 pairs of this thread
    const double w2 = s_w2[j];
    const double two_pi = 6.2831853071795864769;
    int r = tid >> 5;                    // local row 0..7, step 8
#pragma unroll
    for (int k = 0; k < 4; ++k) {
        const double t = (double)(rowBase + r) * w2;   // revolutions
        const double frac = t - rint(t);               // [-0.5, 0.5]
        const float rad = (float)(frac * two_pi);      // [-pi, pi]
        const int pos = r * OUTC + 3 + 2 * j;
        s_tile[pos]     = __sinf(rad);                 // native v_sin_f32
        s_tile[pos + 1] = __cosf(rad);                 // native v_cos_f32
        r += 8;
    }

    // ---- Phase A2: coords + colours via coalesced float4 loads ----
    if (tid < IN_VEC4_PER_BLOCK) {
        const long long inBase = (long long)b * IN_FLOATS_PER_BLOCK;
        const long long f0 = inBase + tid * 4;
        const long long in_total = (long long)n_rows * 6;
        if (f0 + 3 < in_total) {
            const float4 v = reinterpret_cast<const float4*>(pc)[inBase / 4 + tid];
            const float* ve = &v.x;
#pragma unroll
            for (int m = 0; m < 4; ++m) {
                const int fl = tid * 4 + m;            // local input idx 0..191
                const int row = fl / 6;                // magic-mul
                const int c = fl - row * 6;
                const int col = (c < 3) ? c : (c + 64); // 67..69 for colours
                s_tile[row * OUTC + col] = ve[m];
            }
        } else {                                       // ragged tail block
            for (int m = 0; m < 4; ++m) {
                const long long f = f0 + m;
                if (f < in_total) {
                    const float val = pc[f];
                    const int fl = tid * 4 + m;
                    const int row = fl / 6;
                    const int c = fl - row * 6;
                    const int col = (c < 3) ? c : (c + 64);
                    s_tile[row * OUTC + col] = val;
                }
            }
        }
    }
    __syncthreads();

    // ---- Phase B: LDS tile -> global, 16B-aligned float4 stores ----
    const long long outBase = (long long)b * FLOATS_PER_BLOCK;  // multiple of 4
    const long long total = (long long)n_rows * OUTC;
    for (int i = tid; i < VEC4_PER_BLOCK; i += 256) {
        const long long g = outBase + (long long)i * 4;
        if (g + 4 <= total) {
            float4 v;
            v.x = s_tile[i * 4 + 0];
            v.y = s_tile[i * 4 + 1];
            v.z = s_tile[i * 4 + 2];
            v.w = s_tile[i * 4 + 3];
            reinterpret_cast<float4*>(out)[outBase / 4 + i] = v;
        } else {
            for (int m = 0; m < 4; ++m)
                if (g + m < total) out[g + m] = s_tile[i * 4 + m];
        }
    }
}

extern "C" void kernel_launch(void* const* d_in, const int* in_sizes, int n_in,
                              void* d_out, int out_size, void* d_ws, size_t ws_size,
                              hipStream_t stream) {
    const float* pc = (const float*)d_in[0];
    float* out = (float*)d_out;
    const int n_rows = in_sizes[0] / 6;
    const int grid = (n_rows + ROWS_PER_BLOCK - 1) / ROWS_PER_BLOCK;  // 31250
    pe_kernel<<<dim3(grid), dim3(256), 0, stream>>>(pc, out, n_rows);
}